// Round 8
// baseline (1033.548 us; speedup 1.0000x reference)
//
#include <hip/hip_runtime.h>

// LSTM: B=2048, T=512, I=1, H=64, L=2, O=1. fp32 in/out.
// Round 8: r7's wave-specialized skew, but BT=4 / 512 blocks -> 2
// independent blocks per CU (16 waves/CU, 4/SIMD). r7 measured 2845
// cyc/step vs ~1500 busy -> half the step was exposed latency/barrier
// straggle at 2 waves/SIMD. Two barrier-independent blocks interleave:
// one block's drain hides under the other's issue. M-tile now 4/16 real
// (MFMA floor 691 cyc/step/CU — still < step), combine 1 pair/lane.
//   waves 0-3 (L1-group): all 256 G1 cols (64/wave)
//   waves 4-7 (L2-group): all 256 G2 cols
//   phase A: L1 MFMA G1(k)->pD1          | L2 combine h2(k-2)<-pD2 ->aH2
//   phase B: L1 combine h1(k)->aH1[buf]  | L2 MFMA G2(k-1)->pD2
// fp32 accuracy via bf16 hi+lo 3-product split.

#define TT 512
#define HH 64
#define BT 4

typedef __attribute__((ext_vector_type(8))) short short8;
typedef __attribute__((ext_vector_type(4))) float f32x4;

#define MFMA16 __builtin_amdgcn_mfma_f32_16x16x32_bf16

__device__ __forceinline__ float sigm(float x) {
    return __builtin_amdgcn_rcpf(1.f + __expf(-x));
}
__device__ __forceinline__ float tanh_f(float x) {
    float xc = fminf(fmaxf(x, -15.f), 15.f);
    float e = __expf(2.f * xc);
    return (e - 1.f) * __builtin_amdgcn_rcpf(e + 1.f);
}
__device__ __forceinline__ void cvt8(const float* p, short8& hi, short8& lo) {
    #pragma unroll
    for (int i = 0; i < 8; ++i) {
        float v = p[i];
        unsigned short h = (unsigned short)(__float_as_uint(v) >> 16);
        float r = v - __uint_as_float(((unsigned)h) << 16);
        unsigned short l = (unsigned short)(__float_as_uint(r) >> 16);
        hi[i] = (short)h;
        lo[i] = (short)l;
    }
}
__device__ __forceinline__ void split1(float v, unsigned short& h, unsigned short& l) {
    h = (unsigned short)(__float_as_uint(v) >> 16);
    float r = v - __uint_as_float(((unsigned)h) << 16);
    l = (unsigned short)(__float_as_uint(r) >> 16);
}
__device__ __forceinline__ float gate4(float pi, float pf, float pg, float po, float& c) {
    float gi = sigm(pi), gf = sigm(pf), gg = tanh_f(pg), go = sigm(po);
    c = fmaf(gf, c, gi * gg);
    return go * tanh_f(c);
}

__global__ __launch_bounds__(512, 2) void lstm_mfma(
    const float* __restrict__ x,
    const float* __restrict__ Wih0, const float* __restrict__ Whh0,
    const float* __restrict__ bih0, const float* __restrict__ bhh0,
    const float* __restrict__ Wih1, const float* __restrict__ Whh1,
    const float* __restrict__ bih1, const float* __restrict__ bhh1,
    const float* __restrict__ fcW, const float* __restrict__ fcb,
    float* __restrict__ out)
{
    __shared__ float xs[BT][TT + 1];                   // 8.2 KB
    __shared__ __align__(16) float pD1[256][20];       // 20 KB  G1 preacts
    __shared__ __align__(16) float pD2[256][20];       // 20 KB  G2 preacts
    __shared__ __align__(16) short aH1[2][2][2][64][8];// 8 KB [buf][kt][hi/lo][row][e]
    __shared__ __align__(16) short aH2[2][2][64][8];   // 4 KB [kt][hi/lo][row][e]
    __shared__ float hF[BT][HH + 1];
    __shared__ float fcw_s[HH];

    const int t    = threadIdx.x;
    const int lane = t & 63;
    const int w    = t >> 6;          // wave 0..7
    const bool isL1 = (w < 4);
    const int wv   = w & 3;           // group-local wave
    const int ntb  = wv * 64;         // column base (4 N-tiles of 16)
    const int b0   = blockIdx.x * BT;

    // ---- stage x (coalesced rows); zero A-frag buffers ----
    for (int i = t; i < BT * TT; i += 512)
        xs[i >> 9][i & (TT - 1)] = x[(size_t)(b0 + (i >> 9)) * TT + (i & (TT - 1))];
    {
        int* z1 = (int*)aH1;
        for (int i = t; i < 2048; i += 512) z1[i] = 0;
        int* z2 = (int*)aH2;
        for (int i = t; i < 1024; i += 512) z2[i] = 0;
    }
    if (t < HH) fcw_s[t] = fcW[t];

    // ---- persistent B fragments (union across groups) ----
    // L1-wave: kt0..1 from Whh0 (G1).  L2-wave: kt0..1 Wih1, kt2..3 Whh1 (G2).
    short8 bfh[4][4], bfl[4][4];      // [kt][nt]
    {
        const int n_lo = lane & 15;
        const int k8   = (lane >> 4) * 8;
        #pragma unroll
        for (int nt = 0; nt < 4; ++nt) {
            const int col = ntb + nt * 16 + n_lo;
            if (isL1) {
                cvt8(Whh0 + col * HH +      k8, bfh[0][nt], bfl[0][nt]);
                cvt8(Whh0 + col * HH + 32 + k8, bfh[1][nt], bfl[1][nt]);
            } else {
                cvt8(Wih1 + col * HH +      k8, bfh[0][nt], bfl[0][nt]);
                cvt8(Wih1 + col * HH + 32 + k8, bfh[1][nt], bfl[1][nt]);
                cvt8(Whh1 + col * HH +      k8, bfh[2][nt], bfl[2][nt]);
                cvt8(Whh1 + col * HH + 32 + k8, bfh[3][nt], bfl[3][nt]);
            }
        }
    }

    // ---- combine constants: group-lane gl owns ONE pair (cb, cj) ----
    const int gl  = wv * 64 + lane;   // 0..255 within group
    const int cb  = gl & 3;           // batch 0..3
    const int cj  = gl >> 2;          // hidden 0..63
    const int kts = cj >> 5;          // A-frag kt
    const int sla = cb + ((cj >> 3) & 3) * 16;
    const int sel = cj & 7;
    float wA[4], bA[4];
    #pragma unroll
    for (int g = 0; g < 4; ++g) {
        if (isL1) {
            wA[g] = Wih0[g * 64 + cj];
            bA[g] = bih0[g * 64 + cj] + bhh0[g * 64 + cj];
        } else {
            wA[g] = 0.f;
            bA[g] = bih1[g * 64 + cj] + bhh1[g * 64 + cj];
        }
    }
    float cA = 0.f;
    __syncthreads();

    #pragma unroll 2
    for (int k = 0; k < TT; ++k) {
        const int p = k & 1, pn = p ^ 1;

        // ======== phase A ========
        if (isL1) {
            // MFMA G1(k) = Whh0 * h1(k-1)
            short8 a0h = *(const short8*)&aH1[p][0][0][lane][0];
            short8 a0l = *(const short8*)&aH1[p][0][1][lane][0];
            short8 a1h = *(const short8*)&aH1[p][1][0][lane][0];
            short8 a1l = *(const short8*)&aH1[p][1][1][lane][0];
            #pragma unroll
            for (int nt = 0; nt < 4; ++nt) {
                f32x4 acc = {0.f, 0.f, 0.f, 0.f};
                acc = MFMA16(a0h, bfh[0][nt], acc, 0, 0, 0);
                acc = MFMA16(a0h, bfl[0][nt], acc, 0, 0, 0);
                acc = MFMA16(a0l, bfh[0][nt], acc, 0, 0, 0);
                acc = MFMA16(a1h, bfh[1][nt], acc, 0, 0, 0);
                acc = MFMA16(a1h, bfl[1][nt], acc, 0, 0, 0);
                acc = MFMA16(a1l, bfh[1][nt], acc, 0, 0, 0);
                *(f32x4*)&pD1[ntb + nt * 16 + (lane & 15)][(lane >> 4) * 4] = acc;
            }
        } else if (k >= 2) {
            // combine h2(k-2) from pD2
            float h2 = gate4(pD2[cj][cb] + bA[0],       pD2[64 + cj][cb] + bA[1],
                             pD2[128 + cj][cb] + bA[2], pD2[192 + cj][cb] + bA[3], cA);
            unsigned short h, l;
            split1(h2, h, l);
            aH2[kts][0][sla][sel] = (short)h;
            aH2[kts][1][sla][sel] = (short)l;
        }
        __syncthreads();

        // ======== phase B ========
        if (isL1) {
            // combine h1(k) from pD1 (+ x term)
            float xb = xs[cb][k];
            float h1 = gate4(pD1[cj][cb]       + fmaf(wA[0], xb, bA[0]),
                             pD1[64 + cj][cb]  + fmaf(wA[1], xb, bA[1]),
                             pD1[128 + cj][cb] + fmaf(wA[2], xb, bA[2]),
                             pD1[192 + cj][cb] + fmaf(wA[3], xb, bA[3]), cA);
            unsigned short h, l;
            split1(h1, h, l);
            aH1[pn][kts][0][sla][sel] = (short)h;
            aH1[pn][kts][1][sla][sel] = (short)l;
        } else {
            // MFMA G2(k-1) = Wih1*h1(k-1) + Whh1*h2(k-2)   (k=0: junk, ignored)
            short8 a0h = *(const short8*)&aH1[p][0][0][lane][0];
            short8 a0l = *(const short8*)&aH1[p][0][1][lane][0];
            short8 a1h = *(const short8*)&aH1[p][1][0][lane][0];
            short8 a1l = *(const short8*)&aH1[p][1][1][lane][0];
            short8 a2h = *(const short8*)&aH2[0][0][lane][0];
            short8 a2l = *(const short8*)&aH2[0][1][lane][0];
            short8 a3h = *(const short8*)&aH2[1][0][lane][0];
            short8 a3l = *(const short8*)&aH2[1][1][lane][0];
            #pragma unroll
            for (int nt = 0; nt < 4; ++nt) {
                f32x4 acc = {0.f, 0.f, 0.f, 0.f};
                acc = MFMA16(a0h, bfh[0][nt], acc, 0, 0, 0);
                acc = MFMA16(a0h, bfl[0][nt], acc, 0, 0, 0);
                acc = MFMA16(a0l, bfh[0][nt], acc, 0, 0, 0);
                acc = MFMA16(a1h, bfh[1][nt], acc, 0, 0, 0);
                acc = MFMA16(a1h, bfl[1][nt], acc, 0, 0, 0);
                acc = MFMA16(a1l, bfh[1][nt], acc, 0, 0, 0);
                acc = MFMA16(a2h, bfh[2][nt], acc, 0, 0, 0);
                acc = MFMA16(a2h, bfl[2][nt], acc, 0, 0, 0);
                acc = MFMA16(a2l, bfh[2][nt], acc, 0, 0, 0);
                acc = MFMA16(a3h, bfh[3][nt], acc, 0, 0, 0);
                acc = MFMA16(a3h, bfl[3][nt], acc, 0, 0, 0);
                acc = MFMA16(a3l, bfh[3][nt], acc, 0, 0, 0);
                *(f32x4*)&pD2[ntb + nt * 16 + (lane & 15)][(lane >> 4) * 4] = acc;
            }
        }
        __syncthreads();
    }

    // ---- epilogue: finish layer-2 skew (h2(TT-2), then h2(TT-1)) ----
    if (!isL1) {
        float h2 = gate4(pD2[cj][cb] + bA[0],       pD2[64 + cj][cb] + bA[1],
                         pD2[128 + cj][cb] + bA[2], pD2[192 + cj][cb] + bA[3], cA);
        unsigned short h, l;
        split1(h2, h, l);
        aH2[kts][0][sla][sel] = (short)h;
        aH2[kts][1][sla][sel] = (short)l;
    }
    __syncthreads();
    if (!isL1) {
        // MFMA G2(TT-1): h1(TT-1) in aH1[0] (TT even), h2(TT-2) in aH2
        short8 a0h = *(const short8*)&aH1[0][0][0][lane][0];
        short8 a0l = *(const short8*)&aH1[0][0][1][lane][0];
        short8 a1h = *(const short8*)&aH1[0][1][0][lane][0];
        short8 a1l = *(const short8*)&aH1[0][1][1][lane][0];
        short8 a2h = *(const short8*)&aH2[0][0][lane][0];
        short8 a2l = *(const short8*)&aH2[0][1][lane][0];
        short8 a3h = *(const short8*)&aH2[1][0][lane][0];
        short8 a3l = *(const short8*)&aH2[1][1][lane][0];
        #pragma unroll
        for (int nt = 0; nt < 4; ++nt) {
            f32x4 acc = {0.f, 0.f, 0.f, 0.f};
            acc = MFMA16(a0h, bfh[0][nt], acc, 0, 0, 0);
            acc = MFMA16(a0h, bfl[0][nt], acc, 0, 0, 0);
            acc = MFMA16(a0l, bfh[0][nt], acc, 0, 0, 0);
            acc = MFMA16(a1h, bfh[1][nt], acc, 0, 0, 0);
            acc = MFMA16(a1h, bfl[1][nt], acc, 0, 0, 0);
            acc = MFMA16(a1l, bfh[1][nt], acc, 0, 0, 0);
            acc = MFMA16(a2h, bfh[2][nt], acc, 0, 0, 0);
            acc = MFMA16(a2h, bfl[2][nt], acc, 0, 0, 0);
            acc = MFMA16(a2l, bfh[2][nt], acc, 0, 0, 0);
            acc = MFMA16(a3h, bfh[3][nt], acc, 0, 0, 0);
            acc = MFMA16(a3h, bfl[3][nt], acc, 0, 0, 0);
            acc = MFMA16(a3l, bfh[3][nt], acc, 0, 0, 0);
            *(f32x4*)&pD2[ntb + nt * 16 + (lane & 15)][(lane >> 4) * 4] = acc;
        }
    }
    __syncthreads();
    if (!isL1) {
        float h2 = gate4(pD2[cj][cb] + bA[0],       pD2[64 + cj][cb] + bA[1],
                         pD2[128 + cj][cb] + bA[2], pD2[192 + cj][cb] + bA[3], cA);
        hF[cb][cj] = h2;
    }
    __syncthreads();

    // ---- final FC: out[b] = fcW . h2(TT-1)[b] + fcb ----
    if (t < BT) {
        float s = fcb[0];
        #pragma unroll 8
        for (int j = 0; j < HH; ++j)
            s = fmaf(hF[t][j], fcw_s[j], s);
        out[b0 + t] = s;
    }
}

extern "C" void kernel_launch(void* const* d_in, const int* in_sizes, int n_in,
                              void* d_out, int out_size, void* d_ws, size_t ws_size,
                              hipStream_t stream) {
    const float* x    = (const float*)d_in[0];
    const float* Wih0 = (const float*)d_in[1];
    const float* Whh0 = (const float*)d_in[2];
    const float* bih0 = (const float*)d_in[3];
    const float* bhh0 = (const float*)d_in[4];
    const float* Wih1 = (const float*)d_in[5];
    const float* Whh1 = (const float*)d_in[6];
    const float* bih1 = (const float*)d_in[7];
    const float* bhh1 = (const float*)d_in[8];
    const float* fcW  = (const float*)d_in[9];
    const float* fcb  = (const float*)d_in[10];
    float* out = (float*)d_out;

    lstm_mfma<<<dim3(2048 / BT), dim3(512), 0, stream>>>(
        x, Wih0, Whh0, bih0, bhh0, Wih1, Whh1, bih1, bhh1, fcW, fcb, out);
}

// Round 9
// 687.813 us; speedup vs baseline: 1.5027x; 1.5027x over previous
//
#include <hip/hip_runtime.h>

// LSTM: B=2048, T=512, I=1, H=64, L=2, O=1. fp32 in/out.
// Round 9: transposed MFMA (D = W*h). M = gate-rows ordered (j,gate),
// N = batch, A = persistent weight frags (regs/AGPRs), B = h frags (LDS).
// C/D layout (col=lane&15, row=quad*4+reg) => each lane's f32x4 holds all
// 4 gate preacts for one (j, batch): combine is IN-REGISTER on the MFMA
// wave. No pD LDS roundtrip, and ONE barrier/step:
//   waves 0-3: G1: MFMA Whh0*h1(k-1) + x-term -> combine -> h1(k) -> aH1[pn]
//   waves 4-7: G2: MFMA Wih1*h1(k-1)+Whh1*h2(k-2) -> combine -> h2(k-1) -> aH2[pn]
// (h2 runs one step skewed; both groups read only [p] buffers, write [pn].)
// Register note (r8 lesson): pool = 512 regs/SIMD unified VGPR+AGPR ->
// ~220 regs/wave pins us at 2 waves/SIMD; this design accepts that and
// minimizes per-step work instead of chasing occupancy.
// fp32 accuracy via bf16 hi+lo 3-product split (Wh*hh + Wl*hh + Wh*hl).

#define TT 512
#define HH 64
#define BT 8

typedef __attribute__((ext_vector_type(8))) short short8;
typedef __attribute__((ext_vector_type(4))) float f32x4;

#define MFMA16 __builtin_amdgcn_mfma_f32_16x16x32_bf16

__device__ __forceinline__ float sigm(float x) {
    return __builtin_amdgcn_rcpf(1.f + __expf(-x));
}
// NaN-safe tanh: 1 - 2/(1+e^{2x}); x=+inf -> 1, x=-inf -> -1, no clamp.
__device__ __forceinline__ float tanh_f(float x) {
    return 1.f - 2.f * __builtin_amdgcn_rcpf(1.f + __expf(2.f * x));
}
__device__ __forceinline__ void cvt8(const float* p, short8& hi, short8& lo) {
    #pragma unroll
    for (int i = 0; i < 8; ++i) {
        float v = p[i];
        unsigned short h = (unsigned short)(__float_as_uint(v) >> 16);
        float r = v - __uint_as_float(((unsigned)h) << 16);
        unsigned short l = (unsigned short)(__float_as_uint(r) >> 16);
        hi[i] = (short)h;
        lo[i] = (short)l;
    }
}
__device__ __forceinline__ void split1(float v, unsigned short& h, unsigned short& l) {
    h = (unsigned short)(__float_as_uint(v) >> 16);
    float r = v - __uint_as_float(((unsigned)h) << 16);
    l = (unsigned short)(__float_as_uint(r) >> 16);
}
__device__ __forceinline__ float gate4(float pi, float pf, float pg, float po, float& c) {
    float gi = sigm(pi), gf = sigm(pf), gg = tanh_f(pg), go = sigm(po);
    c = fmaf(gf, c, gi * gg);
    return go * tanh_f(c);
}

__global__ __launch_bounds__(512, 2) void lstm_mfma(
    const float* __restrict__ x,
    const float* __restrict__ Wih0, const float* __restrict__ Whh0,
    const float* __restrict__ bih0, const float* __restrict__ bhh0,
    const float* __restrict__ Wih1, const float* __restrict__ Whh1,
    const float* __restrict__ bih1, const float* __restrict__ bhh1,
    const float* __restrict__ fcW, const float* __restrict__ fcb,
    float* __restrict__ out)
{
    __shared__ float xs[BT][TT + 1];                     // 16.4 KB
    // h in MFMA B-layout: [buf][kt][hi/lo][lane][elem]; B[k][n]: n=lane&15,
    // k = kt*32 + (lane>>4)*8 + elem. Batches n>=8 never written => stay 0.
    __shared__ __align__(16) short aH1[2][2][2][64][8];  // 8 KB
    __shared__ __align__(16) short aH2[2][2][2][64][8];  // 8 KB
    __shared__ float hF[BT][HH + 1];
    __shared__ float fcw_s[HH];

    const int t    = threadIdx.x;
    const int lane = t & 63;
    const int w    = t >> 6;          // wave 0..7
    const bool isL1 = (w < 4);
    const int wv   = w & 3;           // group-local wave: owns M-tiles 4wv..4wv+3
    const int b0   = blockIdx.x * BT;
    const int m    = lane & 15;       // A-row-within-tile AND D-col (=batch)
    const int q    = lane >> 4;       // quad

    // ---- stage x; zero both h buffers (h1(-1)=0, h2(-2)=h2(-1)=0) ----
    for (int i = t; i < BT * TT; i += 512)
        xs[i >> 9][i & (TT - 1)] = x[(size_t)(b0 + (i >> 9)) * TT + (i & (TT - 1))];
    {
        int* z1 = (int*)aH1;
        for (int i = t; i < 2048; i += 512) z1[i] = 0;
        int* z2 = (int*)aH2;
        for (int i = t; i < 2048; i += 512) z2[i] = 0;
    }
    if (t < HH) fcw_s[t] = fcW[t];

    // ---- persistent A-frag weights (hi/lo) + combine constants ----
    // A[m'][k] with row m' -> gate-row rho = (m'&3)*64 + 4*mtg + (m'>>2)
    // (rows within a 16-tile ordered j-major: quad qq holds j=4*mtg+qq, gates 0..3)
    // G1 (isL1): kt 0,1 from Whh0.  G2: kt 0,1 Wih1; kt 2,3 Whh1.
    short8 aWh[4][4], aWl[4][4];      // [i][kt]
    float  wxb[4][4], bia[4][4], c[4];
    {
        const float* Ws01 = isL1 ? Whh0 : Wih1;
        #pragma unroll
        for (int i = 0; i < 4; ++i) {
            const int mtg = 4 * wv + i;
            const int rho = (m & 3) * 64 + 4 * mtg + (m >> 2);
            cvt8(Ws01 + rho * HH +      q * 8, aWh[i][0], aWl[i][0]);
            cvt8(Ws01 + rho * HH + 32 + q * 8, aWh[i][1], aWl[i][1]);
            if (!isL1) {
                cvt8(Whh1 + rho * HH +      q * 8, aWh[i][2], aWl[i][2]);
                cvt8(Whh1 + rho * HH + 32 + q * 8, aWh[i][3], aWl[i][3]);
            }
            const int jmy = 4 * mtg + q;   // this lane's j for tile i (combine role)
            #pragma unroll
            for (int v = 0; v < 4; ++v) {
                if (isL1) {
                    wxb[i][v] = Wih0[v * 64 + jmy];
                    bia[i][v] = bih0[v * 64 + jmy] + bhh0[v * 64 + jmy];
                } else {
                    bia[i][v] = bih1[v * 64 + jmy] + bhh1[v * 64 + jmy];
                }
            }
            c[i] = 0.f;
        }
    }
    const int ktj = wv >> 1;          // scatter kt (j in [16wv,16wv+16))

    __syncthreads();

    #pragma unroll 2
    for (int k = 0; k < TT; ++k) {
        const int p = k & 1, pn = p ^ 1;

        if (isL1) {
            // ---- G1: h1(k) from h1(k-1) ----
            short8 bh0 = *(const short8*)&aH1[p][0][0][lane][0];
            short8 bl0 = *(const short8*)&aH1[p][0][1][lane][0];
            short8 bh1 = *(const short8*)&aH1[p][1][0][lane][0];
            short8 bl1 = *(const short8*)&aH1[p][1][1][lane][0];
            float xb = xs[lane & 7][k];
            #pragma unroll
            for (int i = 0; i < 4; ++i) {
                f32x4 acc = {0.f, 0.f, 0.f, 0.f};
                acc = MFMA16(aWh[i][0], bh0, acc, 0, 0, 0);
                acc = MFMA16(aWl[i][0], bh0, acc, 0, 0, 0);
                acc = MFMA16(aWh[i][0], bl0, acc, 0, 0, 0);
                acc = MFMA16(aWh[i][1], bh1, acc, 0, 0, 0);
                acc = MFMA16(aWl[i][1], bh1, acc, 0, 0, 0);
                acc = MFMA16(aWh[i][1], bl1, acc, 0, 0, 0);
                float pi = acc[0] + fmaf(wxb[i][0], xb, bia[i][0]);
                float pf = acc[1] + fmaf(wxb[i][1], xb, bia[i][1]);
                float pg = acc[2] + fmaf(wxb[i][2], xb, bia[i][2]);
                float po = acc[3] + fmaf(wxb[i][3], xb, bia[i][3]);
                float h1 = gate4(pi, pf, pg, po, c[i]);
                if (m < BT) {
                    unsigned short hh, hl;
                    split1(h1, hh, hl);
                    const int j  = 16 * wv + 4 * i + q;
                    const int sl = m + 16 * ((j >> 3) & 3);
                    aH1[pn][ktj][0][sl][j & 7] = (short)hh;
                    aH1[pn][ktj][1][sl][j & 7] = (short)hl;
                }
            }
        } else if (k > 0) {
            // ---- G2: h2(k-1) from h1(k-1), h2(k-2) ----
            short8 b1h0 = *(const short8*)&aH1[p][0][0][lane][0];
            short8 b1l0 = *(const short8*)&aH1[p][0][1][lane][0];
            short8 b1h1 = *(const short8*)&aH1[p][1][0][lane][0];
            short8 b1l1 = *(const short8*)&aH1[p][1][1][lane][0];
            short8 b2h0 = *(const short8*)&aH2[p][0][0][lane][0];
            short8 b2l0 = *(const short8*)&aH2[p][0][1][lane][0];
            short8 b2h1 = *(const short8*)&aH2[p][1][0][lane][0];
            short8 b2l1 = *(const short8*)&aH2[p][1][1][lane][0];
            #pragma unroll
            for (int i = 0; i < 4; ++i) {
                f32x4 acc = {0.f, 0.f, 0.f, 0.f};
                acc = MFMA16(aWh[i][0], b1h0, acc, 0, 0, 0);
                acc = MFMA16(aWl[i][0], b1h0, acc, 0, 0, 0);
                acc = MFMA16(aWh[i][0], b1l0, acc, 0, 0, 0);
                acc = MFMA16(aWh[i][1], b1h1, acc, 0, 0, 0);
                acc = MFMA16(aWl[i][1], b1h1, acc, 0, 0, 0);
                acc = MFMA16(aWh[i][1], b1l1, acc, 0, 0, 0);
                acc = MFMA16(aWh[i][2], b2h0, acc, 0, 0, 0);
                acc = MFMA16(aWl[i][2], b2h0, acc, 0, 0, 0);
                acc = MFMA16(aWh[i][2], b2l0, acc, 0, 0, 0);
                acc = MFMA16(aWh[i][3], b2h1, acc, 0, 0, 0);
                acc = MFMA16(aWl[i][3], b2h1, acc, 0, 0, 0);
                acc = MFMA16(aWh[i][3], b2l1, acc, 0, 0, 0);
                float h2 = gate4(acc[0] + bia[i][0], acc[1] + bia[i][1],
                                 acc[2] + bia[i][2], acc[3] + bia[i][3], c[i]);
                if (m < BT) {
                    unsigned short hh, hl;
                    split1(h2, hh, hl);
                    const int j  = 16 * wv + 4 * i + q;
                    const int sl = m + 16 * ((j >> 3) & 3);
                    aH2[pn][ktj][0][sl][j & 7] = (short)hh;
                    aH2[pn][ktj][1][sl][j & 7] = (short)hl;
                }
            }
        }
        __syncthreads();
    }

    // ---- epilogue: h2(TT-1) from h1(TT-1) (aH1[0]) and h2(TT-2) (aH2[0]) ----
    if (!isL1) {
        short8 b1h0 = *(const short8*)&aH1[0][0][0][lane][0];
        short8 b1l0 = *(const short8*)&aH1[0][0][1][lane][0];
        short8 b1h1 = *(const short8*)&aH1[0][1][0][lane][0];
        short8 b1l1 = *(const short8*)&aH1[0][1][1][lane][0];
        short8 b2h0 = *(const short8*)&aH2[0][0][0][lane][0];
        short8 b2l0 = *(const short8*)&aH2[0][0][1][lane][0];
        short8 b2h1 = *(const short8*)&aH2[0][1][0][lane][0];
        short8 b2l1 = *(const short8*)&aH2[0][1][1][lane][0];
        #pragma unroll
        for (int i = 0; i < 4; ++i) {
            f32x4 acc = {0.f, 0.f, 0.f, 0.f};
            acc = MFMA16(aWh[i][0], b1h0, acc, 0, 0, 0);
            acc = MFMA16(aWl[i][0], b1h0, acc, 0, 0, 0);
            acc = MFMA16(aWh[i][0], b1l0, acc, 0, 0, 0);
            acc = MFMA16(aWh[i][1], b1h1, acc, 0, 0, 0);
            acc = MFMA16(aWl[i][1], b1h1, acc, 0, 0, 0);
            acc = MFMA16(aWh[i][1], b1l1, acc, 0, 0, 0);
            acc = MFMA16(aWh[i][2], b2h0, acc, 0, 0, 0);
            acc = MFMA16(aWl[i][2], b2h0, acc, 0, 0, 0);
            acc = MFMA16(aWh[i][2], b2l0, acc, 0, 0, 0);
            acc = MFMA16(aWh[i][3], b2h1, acc, 0, 0, 0);
            acc = MFMA16(aWl[i][3], b2h1, acc, 0, 0, 0);
            acc = MFMA16(aWh[i][3], b2l1, acc, 0, 0, 0);
            float h2 = gate4(acc[0] + bia[i][0], acc[1] + bia[i][1],
                             acc[2] + bia[i][2], acc[3] + bia[i][3], c[i]);
            if (m < BT) {
                const int j = 16 * wv + 4 * i + q;
                hF[m][j] = h2;
            }
        }
    }
    __syncthreads();

    // ---- final FC: out[b] = fcW . h2(TT-1)[b] + fcb ----
    if (t < BT) {
        float s = fcb[0];
        #pragma unroll 8
        for (int j = 0; j < HH; ++j)
            s = fmaf(hF[t][j], fcw_s[j], s);
        out[b0 + t] = s;
    }
}

extern "C" void kernel_launch(void* const* d_in, const int* in_sizes, int n_in,
                              void* d_out, int out_size, void* d_ws, size_t ws_size,
                              hipStream_t stream) {
    const float* x    = (const float*)d_in[0];
    const float* Wih0 = (const float*)d_in[1];
    const float* Whh0 = (const float*)d_in[2];
    const float* bih0 = (const float*)d_in[3];
    const float* bhh0 = (const float*)d_in[4];
    const float* Wih1 = (const float*)d_in[5];
    const float* Whh1 = (const float*)d_in[6];
    const float* bih1 = (const float*)d_in[7];
    const float* bhh1 = (const float*)d_in[8];
    const float* fcW  = (const float*)d_in[9];
    const float* fcb  = (const float*)d_in[10];
    float* out = (float*)d_out;

    lstm_mfma<<<dim3(2048 / BT), dim3(512), 0, stream>>>(
        x, Wih0, Whh0, bih0, bhh0, Wih1, Whh1, bih1, bhh1, fcW, fcb, out);
}

// Round 12
// 490.493 us; speedup vs baseline: 2.1072x; 1.4023x over previous
//
#include <hip/hip_runtime.h>

// LSTM: B=2048, T=512, I=1, H=64, L=2, O=1. fp32 in/out.
// Round 12: r10/r11 design with the REAL bug fixed.
//   r10 and r11 failed with bit-identical absmax (9.033e-3) => both fed
//   ZEROS to lanes m>=8. Cause: the DPP intrinsic is convergent and was
//   emitted inside the divergent ternary arm (exec = {m>=8}); DPP reads
//   of INACTIVE source lanes return 0 under bound_ctrl. Fix: execute the
//   DPP unconditionally (all 64 lanes active; enclosing branches are
//   wave-uniform), then select. r6 passed with exactly this pattern.
// Design (unchanged):
//  (a) thin-slice waves: 1024 threads = 16 waves (4/SIMD), 2 M-tiles/wave.
//  (b) junk-lane packing: D cols 8..15 are nonexistent batches; DPP fold
//      of tile1 into lanes m>=8 -> ONE fully-packed gate4 round per wave.
// Structure: ONE barrier/step, layer-2 skewed one step:
//   waves 0-7 : G1 = Whh0*h1(k-1) (+x) -> h1(k)   -> aH1[pn]
//   waves 8-15: G2 = Wih1*h1(k-1)+Whh1*h2(k-2) -> h2(k-1) -> aH2[pn]
// fp32 accuracy via bf16 hi+lo 3-product split.

#define TT 512
#define HH 64
#define BT 8

typedef __attribute__((ext_vector_type(8))) short short8;
typedef __attribute__((ext_vector_type(4))) float f32x4;

#define MFMA16 __builtin_amdgcn_mfma_f32_16x16x32_bf16

__device__ __forceinline__ float sigm(float x) {
    return __builtin_amdgcn_rcpf(1.f + __expf(-x));
}
// NaN-safe tanh: 1 - 2/(1+e^{2x})
__device__ __forceinline__ float tanh_f(float x) {
    return 1.f - 2.f * __builtin_amdgcn_rcpf(1.f + __expf(2.f * x));
}
__device__ __forceinline__ void cvt8(const float* p, short8& hi, short8& lo) {
    #pragma unroll
    for (int i = 0; i < 8; ++i) {
        float v = p[i];
        unsigned short h = (unsigned short)(__float_as_uint(v) >> 16);
        float r = v - __uint_as_float(((unsigned)h) << 16);
        unsigned short l = (unsigned short)(__float_as_uint(r) >> 16);
        hi[i] = (short)h;
        lo[i] = (short)l;
    }
}
__device__ __forceinline__ void split1(float v, unsigned short& h, unsigned short& l) {
    h = (unsigned short)(__float_as_uint(v) >> 16);
    float r = v - __uint_as_float(((unsigned)h) << 16);
    l = (unsigned short)(__float_as_uint(r) >> 16);
}
__device__ __forceinline__ float gate4(float pi, float pf, float pg, float po, float& c) {
    float gi = sigm(pi), gf = sigm(pf), gg = tanh_f(pg), go = sigm(po);
    c = fmaf(gf, c, gi * gg);
    return go * tanh_f(c);
}
// lane i <- lane (i^8) within each row of 16 (row_ror:8, HW-verified r6).
// MUST be called with all 64 lanes active (convergent; inactive source
// lanes read as 0 under bound_ctrl).
__device__ __forceinline__ float dpp_ror8(float v) {
    return __int_as_float(__builtin_amdgcn_update_dpp(
        0, __float_as_int(v), 0x128, 0xF, 0xF, true));
}

__global__ __launch_bounds__(1024) void lstm_mfma(
    const float* __restrict__ x,
    const float* __restrict__ Wih0, const float* __restrict__ Whh0,
    const float* __restrict__ bih0, const float* __restrict__ bhh0,
    const float* __restrict__ Wih1, const float* __restrict__ Whh1,
    const float* __restrict__ bih1, const float* __restrict__ bhh1,
    const float* __restrict__ fcW, const float* __restrict__ fcb,
    float* __restrict__ out)
{
    __shared__ float xs[BT][TT + 1];                     // 16.4 KB
    // h in MFMA B-layout: [buf][kt][hi/lo][lane][elem]; B[k][n]: n=lane&15,
    // k = kt*32 + (lane>>4)*8 + elem. Batches n>=8 never written => stay 0.
    __shared__ __align__(16) short aH1[2][2][2][64][8];  // 8 KB
    __shared__ __align__(16) short aH2[2][2][2][64][8];  // 8 KB
    __shared__ float hF[BT][HH + 1];
    __shared__ float fcw_s[HH];

    const int t    = threadIdx.x;
    const int lane = t & 63;
    const int w    = t >> 6;          // wave 0..15
    const bool isL1 = (w < 8);
    const int wv   = w & 7;           // group-local wave: owns M-tiles 2wv, 2wv+1
    const int b0   = blockIdx.x * BT;
    const int m    = lane & 15;       // A-row-within-tile AND D-col (=batch)
    const int q    = lane >> 4;       // quad

    // ---- stage x; zero both h buffers ----
    for (int i = t; i < BT * TT; i += 1024)
        xs[i >> 9][i & (TT - 1)] = x[(size_t)(b0 + (i >> 9)) * TT + (i & (TT - 1))];
    {
        int* z1 = (int*)aH1;
        for (int i = t; i < 2048; i += 1024) z1[i] = 0;
        int* z2 = (int*)aH2;
        for (int i = t; i < 2048; i += 1024) z2[i] = 0;
    }
    if (t < HH) fcw_s[t] = fcW[t];

    // ---- persistent A-frag weights (hi/lo): 2 tiles per wave ----
    // A-row m in tile mtg -> gate-row rho = (m&3)*64 + 4*mtg + (m>>2)
    // G1 (isL1): kt 0,1 from Whh0.  G2: kt 0,1 Wih1; kt 2,3 Whh1.
    short8 aWh[2][4], aWl[2][4];      // [i][kt]
    {
        const float* Ws01 = isL1 ? Whh0 : Wih1;
        #pragma unroll
        for (int i = 0; i < 2; ++i) {
            const int mtg = 2 * wv + i;
            const int rho = (m & 3) * 64 + 4 * mtg + (m >> 2);
            cvt8(Ws01 + rho * HH +      q * 8, aWh[i][0], aWl[i][0]);
            cvt8(Ws01 + rho * HH + 32 + q * 8, aWh[i][1], aWl[i][1]);
            if (!isL1) {
                cvt8(Whh1 + rho * HH +      q * 8, aWh[i][2], aWl[i][2]);
                cvt8(Whh1 + rho * HH + 32 + q * 8, aWh[i][3], aWl[i][3]);
            }
        }
    }

    // ---- packed combine constants: lane handles (jpk, bpk) ----
    // tile select ts = (m>=8): lanes m>=8 take tile1's pairs via DPP pack.
    const int ts  = (m >> 3) & 1;
    const int jpk = 8 * wv + 4 * ts + q;   // this lane's hidden unit
    const int bpk = m & 7;                 // this lane's batch
    float wxb[4], bia[4];
    #pragma unroll
    for (int v = 0; v < 4; ++v) {
        if (isL1) {
            wxb[v] = Wih0[v * 64 + jpk];
            bia[v] = bih0[v * 64 + jpk] + bhh0[v * 64 + jpk];
        } else {
            wxb[v] = 0.f;
            bia[v] = bih1[v * 64 + jpk] + bhh1[v * 64 + jpk];
        }
    }
    // scatter indices for (jpk, bpk) into B-layout
    const int skt = jpk >> 5;
    const int ssl = bpk + 16 * ((jpk >> 3) & 3);
    const int sse = jpk & 7;
    float c = 0.f;

    __syncthreads();

    #pragma unroll 2
    for (int k = 0; k < TT; ++k) {
        const int p = k & 1, pn = p ^ 1;

        if (isL1) {
            // ---- G1: h1(k) from h1(k-1) ----
            short8 bh0 = *(const short8*)&aH1[p][0][0][lane][0];
            short8 bl0 = *(const short8*)&aH1[p][0][1][lane][0];
            short8 bh1 = *(const short8*)&aH1[p][1][0][lane][0];
            short8 bl1 = *(const short8*)&aH1[p][1][1][lane][0];
            f32x4 acc0 = {0.f, 0.f, 0.f, 0.f}, acc1 = acc0;
            acc0 = MFMA16(aWh[0][0], bh0, acc0, 0, 0, 0);
            acc0 = MFMA16(aWl[0][0], bh0, acc0, 0, 0, 0);
            acc0 = MFMA16(aWh[0][0], bl0, acc0, 0, 0, 0);
            acc0 = MFMA16(aWh[0][1], bh1, acc0, 0, 0, 0);
            acc0 = MFMA16(aWl[0][1], bh1, acc0, 0, 0, 0);
            acc0 = MFMA16(aWh[0][1], bl1, acc0, 0, 0, 0);
            acc1 = MFMA16(aWh[1][0], bh0, acc1, 0, 0, 0);
            acc1 = MFMA16(aWl[1][0], bh0, acc1, 0, 0, 0);
            acc1 = MFMA16(aWh[1][0], bl0, acc1, 0, 0, 0);
            acc1 = MFMA16(aWh[1][1], bh1, acc1, 0, 0, 0);
            acc1 = MFMA16(aWl[1][1], bh1, acc1, 0, 0, 0);
            acc1 = MFMA16(aWh[1][1], bl1, acc1, 0, 0, 0);
            // DPP executed unconditionally (all lanes active), THEN select.
            f32x4 mv, pk;
            #pragma unroll
            for (int r = 0; r < 4; ++r) mv[r] = dpp_ror8(acc1[r]);
            #pragma unroll
            for (int r = 0; r < 4; ++r) pk[r] = (m < 8) ? acc0[r] : mv[r];
            float xb = xs[bpk][k];
            float h1 = gate4(pk[0] + fmaf(wxb[0], xb, bia[0]),
                             pk[1] + fmaf(wxb[1], xb, bia[1]),
                             pk[2] + fmaf(wxb[2], xb, bia[2]),
                             pk[3] + fmaf(wxb[3], xb, bia[3]), c);
            unsigned short hh, hl;
            split1(h1, hh, hl);
            aH1[pn][skt][0][ssl][sse] = (short)hh;
            aH1[pn][skt][1][ssl][sse] = (short)hl;
        } else if (k > 0) {
            // ---- G2: h2(k-1) from h1(k-1), h2(k-2) ----
            short8 b1h0 = *(const short8*)&aH1[p][0][0][lane][0];
            short8 b1l0 = *(const short8*)&aH1[p][0][1][lane][0];
            short8 b1h1 = *(const short8*)&aH1[p][1][0][lane][0];
            short8 b1l1 = *(const short8*)&aH1[p][1][1][lane][0];
            short8 b2h0 = *(const short8*)&aH2[p][0][0][lane][0];
            short8 b2l0 = *(const short8*)&aH2[p][0][1][lane][0];
            short8 b2h1 = *(const short8*)&aH2[p][1][0][lane][0];
            short8 b2l1 = *(const short8*)&aH2[p][1][1][lane][0];
            f32x4 acc0 = {0.f, 0.f, 0.f, 0.f}, acc1 = acc0;
            acc0 = MFMA16(aWh[0][0], b1h0, acc0, 0, 0, 0);
            acc0 = MFMA16(aWl[0][0], b1h0, acc0, 0, 0, 0);
            acc0 = MFMA16(aWh[0][0], b1l0, acc0, 0, 0, 0);
            acc0 = MFMA16(aWh[0][1], b1h1, acc0, 0, 0, 0);
            acc0 = MFMA16(aWl[0][1], b1h1, acc0, 0, 0, 0);
            acc0 = MFMA16(aWh[0][1], b1l1, acc0, 0, 0, 0);
            acc0 = MFMA16(aWh[0][2], b2h0, acc0, 0, 0, 0);
            acc0 = MFMA16(aWl[0][2], b2h0, acc0, 0, 0, 0);
            acc0 = MFMA16(aWh[0][2], b2l0, acc0, 0, 0, 0);
            acc0 = MFMA16(aWh[0][3], b2h1, acc0, 0, 0, 0);
            acc0 = MFMA16(aWl[0][3], b2h1, acc0, 0, 0, 0);
            acc0 = MFMA16(aWh[0][3], b2l1, acc0, 0, 0, 0);
            acc1 = MFMA16(aWh[1][0], b1h0, acc1, 0, 0, 0);
            acc1 = MFMA16(aWl[1][0], b1h0, acc1, 0, 0, 0);
            acc1 = MFMA16(aWh[1][0], b1l0, acc1, 0, 0, 0);
            acc1 = MFMA16(aWh[1][1], b1h1, acc1, 0, 0, 0);
            acc1 = MFMA16(aWl[1][1], b1h1, acc1, 0, 0, 0);
            acc1 = MFMA16(aWh[1][1], b1l1, acc1, 0, 0, 0);
            acc1 = MFMA16(aWh[1][2], b2h0, acc1, 0, 0, 0);
            acc1 = MFMA16(aWl[1][2], b2h0, acc1, 0, 0, 0);
            acc1 = MFMA16(aWh[1][2], b2l0, acc1, 0, 0, 0);
            acc1 = MFMA16(aWh[1][3], b2h1, acc1, 0, 0, 0);
            acc1 = MFMA16(aWl[1][3], b2h1, acc1, 0, 0, 0);
            acc1 = MFMA16(aWh[1][3], b2l1, acc1, 0, 0, 0);
            f32x4 mv, pk;
            #pragma unroll
            for (int r = 0; r < 4; ++r) mv[r] = dpp_ror8(acc1[r]);
            #pragma unroll
            for (int r = 0; r < 4; ++r) pk[r] = (m < 8) ? acc0[r] : mv[r];
            float h2 = gate4(pk[0] + bia[0], pk[1] + bia[1],
                             pk[2] + bia[2], pk[3] + bia[3], c);
            unsigned short hh, hl;
            split1(h2, hh, hl);
            aH2[pn][skt][0][ssl][sse] = (short)hh;
            aH2[pn][skt][1][ssl][sse] = (short)hl;
        }
        __syncthreads();
    }

    // ---- epilogue: h2(TT-1) from h1(TT-1) (aH1[0]) and h2(TT-2) (aH2[0]) ----
    if (!isL1) {
        short8 b1h0 = *(const short8*)&aH1[0][0][0][lane][0];
        short8 b1l0 = *(const short8*)&aH1[0][0][1][lane][0];
        short8 b1h1 = *(const short8*)&aH1[0][1][0][lane][0];
        short8 b1l1 = *(const short8*)&aH1[0][1][1][lane][0];
        short8 b2h0 = *(const short8*)&aH2[0][0][0][lane][0];
        short8 b2l0 = *(const short8*)&aH2[0][0][1][lane][0];
        short8 b2h1 = *(const short8*)&aH2[0][1][0][lane][0];
        short8 b2l1 = *(const short8*)&aH2[0][1][1][lane][0];
        f32x4 acc0 = {0.f, 0.f, 0.f, 0.f}, acc1 = acc0;
        acc0 = MFMA16(aWh[0][0], b1h0, acc0, 0, 0, 0);
        acc0 = MFMA16(aWl[0][0], b1h0, acc0, 0, 0, 0);
        acc0 = MFMA16(aWh[0][0], b1l0, acc0, 0, 0, 0);
        acc0 = MFMA16(aWh[0][1], b1h1, acc0, 0, 0, 0);
        acc0 = MFMA16(aWl[0][1], b1h1, acc0, 0, 0, 0);
        acc0 = MFMA16(aWh[0][1], b1l1, acc0, 0, 0, 0);
        acc0 = MFMA16(aWh[0][2], b2h0, acc0, 0, 0, 0);
        acc0 = MFMA16(aWl[0][2], b2h0, acc0, 0, 0, 0);
        acc0 = MFMA16(aWh[0][2], b2l0, acc0, 0, 0, 0);
        acc0 = MFMA16(aWh[0][3], b2h1, acc0, 0, 0, 0);
        acc0 = MFMA16(aWl[0][3], b2h1, acc0, 0, 0, 0);
        acc0 = MFMA16(aWh[0][3], b2l1, acc0, 0, 0, 0);
        acc1 = MFMA16(aWh[1][0], b1h0, acc1, 0, 0, 0);
        acc1 = MFMA16(aWl[1][0], b1h0, acc1, 0, 0, 0);
        acc1 = MFMA16(aWh[1][0], b1l0, acc1, 0, 0, 0);
        acc1 = MFMA16(aWh[1][1], b1h1, acc1, 0, 0, 0);
        acc1 = MFMA16(aWl[1][1], b1h1, acc1, 0, 0, 0);
        acc1 = MFMA16(aWh[1][1], b1l1, acc1, 0, 0, 0);
        acc1 = MFMA16(aWh[1][2], b2h0, acc1, 0, 0, 0);
        acc1 = MFMA16(aWl[1][2], b2h0, acc1, 0, 0, 0);
        acc1 = MFMA16(aWh[1][2], b2l0, acc1, 0, 0, 0);
        acc1 = MFMA16(aWh[1][3], b2h1, acc1, 0, 0, 0);
        acc1 = MFMA16(aWl[1][3], b2h1, acc1, 0, 0, 0);
        acc1 = MFMA16(aWh[1][3], b2l1, acc1, 0, 0, 0);
        f32x4 mv, pk;
        #pragma unroll
        for (int r = 0; r < 4; ++r) mv[r] = dpp_ror8(acc1[r]);
        #pragma unroll
        for (int r = 0; r < 4; ++r) pk[r] = (m < 8) ? acc0[r] : mv[r];
        float h2 = gate4(pk[0] + bia[0], pk[1] + bia[1],
                         pk[2] + bia[2], pk[3] + bia[3], c);
        hF[bpk][jpk] = h2;
    }
    __syncthreads();

    // ---- final FC: out[b] = fcW . h2(TT-1)[b] + fcb ----
    if (t < BT) {
        float s = fcb[0];
        #pragma unroll 8
        for (int j = 0; j < HH; ++j)
            s = fmaf(hF[t][j], fcw_s[j], s);
        out[b0 + t] = s;
    }
}

extern "C" void kernel_launch(void* const* d_in, const int* in_sizes, int n_in,
                              void* d_out, int out_size, void* d_ws, size_t ws_size,
                              hipStream_t stream) {
    const float* x    = (const float*)d_in[0];
    const float* Wih0 = (const float*)d_in[1];
    const float* Whh0 = (const float*)d_in[2];
    const float* bih0 = (const float*)d_in[3];
    const float* bhh0 = (const float*)d_in[4];
    const float* Wih1 = (const float*)d_in[5];
    const float* Whh1 = (const float*)d_in[6];
    const float* bih1 = (const float*)d_in[7];
    const float* bhh1 = (const float*)d_in[8];
    const float* fcW  = (const float*)d_in[9];
    const float* fcb  = (const float*)d_in[10];
    float* out = (float*)d_out;

    lstm_mfma<<<dim3(2048 / BT), dim3(1024), 0, stream>>>(
        x, Wih0, Whh0, bih0, bhh0, Wih1, Whh1, bih1, bhh1, fcW, fcb, out);
}